// Round 1
// baseline (1964.902 us; speedup 1.0000x reference)
//
#include <hip/hip_runtime.h>
#include <math.h>

#define N 343          // 7*7*7 tokens per window
#define DIM 128
#define HEADS 4
#define DH 32

// ---------------------------------------------------------------------------
// Kernel 1: gather relative-position bias once (window-independent).
// Layout biasT[h][j][i] so that phase-2 (lane = query row i, loop over j)
// reads it coalesced.
// ---------------------------------------------------------------------------
__global__ __launch_bounds__(256) void bias_gather_kernel(
    const float* __restrict__ bias_table, const int* __restrict__ rel_idx,
    float* __restrict__ biasT) {
  int idx = blockIdx.x * 256 + threadIdx.x;
  if (idx >= N * N) return;
  int j = idx / N;
  int i = idx - j * N;
  int r = rel_idx[i * N + j];
#pragma unroll
  for (int h = 0; h < HEADS; ++h)
    biasT[((size_t)h * N + j) * N + i] = bias_table[r * HEADS + h];
}

// ---------------------------------------------------------------------------
// Kernel 2: fused QKV-projection + attention for one (window, head).
// Block = (window, head). 384 threads; thread i owns query row i (i < 343).
// Phase 1: stage x (32-d chunks) + W slice in LDS, accumulate q,k,v
//          (96 fp32 accumulators per thread). k,v -> LDS; q stays in regs.
// Phase 2: online-softmax flash loop over j; k/v LDS reads are wave-uniform
//          broadcasts (conflict-free); bias read coalesced from biasT.
// Writes O1[w, i, h*32+c] into d_out (head-concat layout).
// ---------------------------------------------------------------------------
__global__ __launch_bounds__(384, 1) void attn_kernel(
    const float* __restrict__ x, const float* __restrict__ wqkv,
    const float* __restrict__ biasT, float* __restrict__ out) {
  const int w = blockIdx.x;
  const int h = blockIdx.y;
  const int tid = threadIdx.x;

  // pad 36 -> 144B row stride: 16B-aligned (b128 reads), writes ~8-way once.
  __shared__ float kb[N][36];
  __shared__ float vb[N][36];
  __shared__ float xl[N][33];   // x chunk, padded for conflict-free reads
  __shared__ float wsl[32][96]; // W slice chunk: [d][{q,k,v}*32+c]

  const float* xw = x + (size_t)w * N * DIM;

  float acc[96];
#pragma unroll
  for (int c = 0; c < 96; ++c) acc[c] = 0.f;

  for (int dc = 0; dc < DIM; dc += 32) {
    // stage x[:, dc:dc+32] (coalesced)
    for (int idx = tid; idx < N * 32; idx += 384) {
      int r = idx >> 5, col = idx & 31;
      xl[r][col] = xw[r * DIM + dc + col];
    }
    // stage W slice for this head: cols {p*128 + h*32 + c}, p in {q,k,v}
    for (int idx = tid; idx < 32 * 96; idx += 384) {
      int d = idx / 96, pc = idx - d * 96;
      int p = pc >> 5, c = pc & 31;
      wsl[d][pc] = wqkv[(size_t)(dc + d) * (3 * DIM) + p * DIM + h * DH + c];
    }
    __syncthreads();
    if (tid < N) {
      for (int d = 0; d < 32; ++d) {
        float xv = xl[tid][d];
#pragma unroll
        for (int c = 0; c < 96; ++c) acc[c] += xv * wsl[d][c];
      }
    }
    __syncthreads();
  }

  float q[DH];
  const float scale = 0.17677669529663687f; // 32^-0.5
  if (tid < N) {
#pragma unroll
    for (int c = 0; c < DH; ++c) {
      q[c] = acc[c] * scale;
      kb[tid][c] = acc[32 + c];
      vb[tid][c] = acc[64 + c];
    }
  }
  __syncthreads();

  if (tid < N) {
    const float* bT = biasT + (size_t)h * N * N;
    float m = -INFINITY, l = 0.f;
    float o[DH];
#pragma unroll
    for (int c = 0; c < DH; ++c) o[c] = 0.f;

    for (int j = 0; j < N; ++j) {
      // 4-way split dot to break the serial FMA chain
      float s0 = 0.f, s1 = 0.f, s2 = 0.f, s3 = 0.f;
#pragma unroll
      for (int c = 0; c < DH; c += 4) {
        s0 += q[c]     * kb[j][c];
        s1 += q[c + 1] * kb[j][c + 1];
        s2 += q[c + 2] * kb[j][c + 2];
        s3 += q[c + 3] * kb[j][c + 3];
      }
      float s = (s0 + s1) + (s2 + s3) + bT[j * N + tid];

      if (s > m) {  // rare after warm-up (~ln(343) times per row)
        float rr = __expf(m - s);
#pragma unroll
        for (int c = 0; c < DH; ++c) o[c] *= rr;
        l *= rr;
        m = s;
      }
      float p = __expf(s - m);
      l += p;
#pragma unroll
      for (int c = 0; c < DH; ++c) o[c] += p * vb[j][c];
    }

    float inv = 1.f / l;
    float* orow = out + ((size_t)w * N + tid) * DIM + h * DH;
#pragma unroll
    for (int c = 0; c < DH; c += 4) {
      *reinterpret_cast<float4*>(orow + c) =
          make_float4(o[c] * inv, o[c + 1] * inv, o[c + 2] * inv, o[c + 3] * inv);
    }
  }
}

// ---------------------------------------------------------------------------
// Kernel 3: out-projection, in-place on d_out. One block per window.
// 64-row tiles staged to LDS before being overwritten -> in-place is safe.
// Wave layout: cb = tid>>6 (uniform per wave) so wl reads are broadcasts.
// ---------------------------------------------------------------------------
__global__ __launch_bounds__(256, 1) void proj_kernel(
    const float* __restrict__ wout, float* __restrict__ out) {
  const int w = blockIdx.x;
  const int tid = threadIdx.x;
  __shared__ float wl[DIM][DIM];
  __shared__ float xt[64][129];

  for (int idx = tid; idx < DIM * DIM; idx += 256)
    wl[idx >> 7][idx & 127] = wout[idx];

  const int cb = tid >> 6;  // wave-uniform column block
  const int r = tid & 63;

  for (int t0 = 0; t0 < N; t0 += 64) {
    __syncthreads();  // previous tile fully consumed (also covers wl load)
    for (int idx = tid; idx < 64 * DIM; idx += 256) {
      int rr = idx >> 7, c = idx & 127;
      int row = t0 + rr;
      xt[rr][c] = (row < N) ? out[((size_t)w * N + row) * DIM + c] : 0.f;
    }
    __syncthreads();

    float acc[32];
#pragma unroll
    for (int c = 0; c < 32; ++c) acc[c] = 0.f;
    for (int d = 0; d < DIM; ++d) {
      float xv = xt[r][d];
#pragma unroll
      for (int c = 0; c < 32; ++c) acc[c] += xv * wl[d][cb * 32 + c];
    }

    int row = t0 + r;
    if (row < N) {
      float* orow = out + ((size_t)w * N + row) * DIM + cb * 32;
#pragma unroll
      for (int c = 0; c < 32; c += 4)
        *reinterpret_cast<float4*>(orow + c) =
            make_float4(acc[c], acc[c + 1], acc[c + 2], acc[c + 3]);
    }
  }
}

// ---------------------------------------------------------------------------
extern "C" void kernel_launch(void* const* d_in, const int* in_sizes, int n_in,
                              void* d_out, int out_size, void* d_ws, size_t ws_size,
                              hipStream_t stream) {
  const float* x          = (const float*)d_in[0];
  const float* w_qkv      = (const float*)d_in[1];
  const float* w_out      = (const float*)d_in[2];
  const float* bias_table = (const float*)d_in[3];
  const int*   rel_idx    = (const int*)d_in[4];
  float* out   = (float*)d_out;
  float* biasT = (float*)d_ws;  // 4*343*343*4 B = 1.88 MB

  const int B = in_sizes[0] / (N * DIM);  // 512 windows

  bias_gather_kernel<<<(N * N + 255) / 256, 256, 0, stream>>>(bias_table,
                                                              rel_idx, biasT);
  dim3 ga(B, HEADS);
  attn_kernel<<<ga, 384, 0, stream>>>(x, w_qkv, biasT, out);
  proj_kernel<<<B, 256, 0, stream>>>(w_out, out);
}

// Round 2
// 476.164 us; speedup vs baseline: 4.1265x; 4.1265x over previous
//
#include <hip/hip_runtime.h>
#include <math.h>

#define N 343        // 7*7*7 tokens per window
#define NP 352       // padded to 11 tiles of 32
#define MTILES 11
#define DIM 128
#define HEADS 4
#define DH 32

typedef float  f32x16 __attribute__((ext_vector_type(16)));
typedef short  short8 __attribute__((ext_vector_type(8)));
typedef unsigned uint4v __attribute__((ext_vector_type(4)));

// ---- manual bf16 helpers (RNE), no header-API dependence -----------------
static __device__ __forceinline__ unsigned short bf16u(float a) {
  unsigned u = __builtin_bit_cast(unsigned, a);
  unsigned r = u + 0x7fffu + ((u >> 16) & 1u);
  return (unsigned short)(r >> 16);
}
static __device__ __forceinline__ float bf16tof(unsigned short h) {
  return __builtin_bit_cast(float, ((unsigned)h) << 16);
}
static __device__ __forceinline__ unsigned pack2bf(float a, float b) {
  return (unsigned)bf16u(a) | ((unsigned)bf16u(b) << 16);
}
static __device__ __forceinline__ void split2(float a, float b,
                                              unsigned& hi, unsigned& lo) {
  unsigned short ha = bf16u(a), hb = bf16u(b);
  hi = (unsigned)ha | ((unsigned)hb << 16);
  lo = (unsigned)bf16u(a - bf16tof(ha)) | ((unsigned)bf16u(b - bf16tof(hb)) << 16);
}

// ---------------------------------------------------------------------------
// Kernel 1: padded bias gather. biasP[h][j][i], j>=343 -> -1e30 (masks pad
// keys so the attention hot loop needs no masking logic at all).
// ---------------------------------------------------------------------------
__global__ __launch_bounds__(256) void bias_kernel(
    const float* __restrict__ table, const int* __restrict__ rel,
    float* __restrict__ biasP) {
  int idx = blockIdx.x * 256 + threadIdx.x;
  if (idx >= HEADS * NP * NP) return;
  int h = idx / (NP * NP);
  int rem = idx - h * NP * NP;
  int j = rem / NP;
  int i = rem - j * NP;
  float v;
  if (j >= N) v = -1e30f;
  else if (i >= N) v = 0.f;
  else v = table[rel[i * N + j] * HEADS + h];
  biasP[idx] = v;
}

// ---------------------------------------------------------------------------
// Kernel 2: fused QKV projection + attention, one block per (window, head).
// 256 threads = 4 waves; 32x32x16 bf16 MFMA everywhere.
// Phase 1: QKV = X @ Wqkv slice with hi/lo split (3 mfma) -> Q,K (row-major)
//          and V (transposed) as bf16 in LDS.
// Phase 2: per M-tile flash loop over j-tiles: swapped QK^T (lane owns one
//          query row), in-register online softmax, P->A-frag via pack+shfl,
//          PV mfma. No LDS writes / barriers in the hot loop.
// ---------------------------------------------------------------------------
__global__ __launch_bounds__(256, 2) void attn_kernel(
    const float* __restrict__ x, const float* __restrict__ wqkv,
    const float* __restrict__ biasP, float* __restrict__ out) {
  const int h    = blockIdx.x;
  const int w    = blockIdx.y;
  const int tid  = threadIdx.x;
  const int lane = tid & 63;
  const int wv   = tid >> 6;
  const int l31  = lane & 31;
  const int half = lane >> 5;

  __shared__ __align__(16) char smem[79872];
  // phase-1 views
  unsigned short* Xh = (unsigned short*)smem;             // [352][40] bf16 hi
  unsigned short* Xl = (unsigned short*)(smem + 28160);   // [352][40] bf16 lo
  unsigned short* Wh = (unsigned short*)(smem + 56320);   // [96][40]
  unsigned short* Wl = (unsigned short*)(smem + 64000);   // [96][40]
  // phase-2 views (reuse same space)
  unsigned short* Qb = (unsigned short*)smem;             // [352][40]
  unsigned short* Kb = (unsigned short*)(smem + 28160);   // [352][40]
  unsigned short* Vt = (unsigned short*)(smem + 56320);   // [32][368]

  const float* xw = x + (size_t)w * (N * DIM);

  // wave -> M-tiles (clamp duplicates tile 10 for wave 3; benign)
  int mt[3];
#pragma unroll
  for (int t = 0; t < 3; ++t) { mt[t] = wv + 4 * t; if (mt[t] > 10) mt[t] = 10; }

  // ---------------- Phase 1: QKV projection ----------------
  f32x16 acc[3][3];
#pragma unroll
  for (int t = 0; t < 3; ++t)
#pragma unroll
    for (int nt = 0; nt < 3; ++nt)
#pragma unroll
      for (int r = 0; r < 16; ++r) acc[t][nt][r] = 0.f;

  for (int kc = 0; kc < 4; ++kc) {
    __syncthreads();
    // stage X[:, kc*32 .. +32) as hi/lo bf16 pairs (5632 float2 / 256 thr)
#pragma unroll
    for (int p = 0; p < 22; ++p) {
      int idx = tid + p * 256;
      int row = idx >> 4, cp = (idx & 15) << 1;
      float a = 0.f, b = 0.f;
      if (row < N) {
        const float* g = xw + row * DIM + kc * 32 + cp;
        a = g[0]; b = g[1];
      }
      unsigned hi, lo; split2(a, b, hi, lo);
      *(unsigned*)&Xh[row * 40 + cp] = hi;
      *(unsigned*)&Xl[row * 40 + cp] = lo;
    }
    // stage W slice transposed: Wt[c 0..95][k 0..31]
#pragma unroll
    for (int p = 0; p < 12; ++p) {
      int idx = tid + p * 256;
      int k = idx / 96, c = idx - k * 96;
      int col = ((c >> 5) << 7) + h * DH + (c & 31);
      float v = wqkv[(size_t)(kc * 32 + k) * (3 * DIM) + col];
      unsigned short hv = bf16u(v);
      Wh[c * 40 + k] = hv;
      Wl[c * 40 + k] = bf16u(v - bf16tof(hv));
    }
    __syncthreads();
#pragma unroll
    for (int t = 0; t < 3; ++t) {
      int rb = (mt[t] * 32 + l31) * 40;
#pragma unroll
      for (int kk = 0; kk < 2; ++kk) {
        short8 ah = *(const short8*)&Xh[rb + kk * 16 + half * 8];
        short8 al = *(const short8*)&Xl[rb + kk * 16 + half * 8];
#pragma unroll
        for (int nt = 0; nt < 3; ++nt) {
          int wb = (nt * 32 + l31) * 40 + kk * 16 + half * 8;
          short8 bh = *(const short8*)&Wh[wb];
          short8 bl = *(const short8*)&Wl[wb];
          acc[t][nt] = __builtin_amdgcn_mfma_f32_32x32x16_bf16(ah, bh, acc[t][nt], 0, 0, 0);
          acc[t][nt] = __builtin_amdgcn_mfma_f32_32x32x16_bf16(ah, bl, acc[t][nt], 0, 0, 0);
          acc[t][nt] = __builtin_amdgcn_mfma_f32_32x32x16_bf16(al, bh, acc[t][nt], 0, 0, 0);
        }
      }
    }
  }

  // ---------------- phase boundary: regs -> Q/K/Vt LDS ----------------
  __syncthreads();
  const float scale = 0.17677669529663687f;  // 32^-0.5
#pragma unroll
  for (int t = 0; t < 3; ++t) {
#pragma unroll
    for (int r = 0; r < 16; ++r) {
      int iD = (r & 3) + ((r >> 2) << 3) + (half << 2);
      int i = mt[t] * 32 + iD;
      Qb[i * 40 + l31] = bf16u(acc[t][0][r] * scale);
      Kb[i * 40 + l31] = bf16u(acc[t][1][r]);
      Vt[l31 * 368 + i] = bf16u(acc[t][2][r]);
    }
  }
  __syncthreads();

  // ---------------- Phase 2: attention ----------------
  const float* bh_ptr = biasP + (size_t)h * NP * NP;
  float* outw = out + (size_t)w * N * DIM + h * DH;

#pragma unroll
  for (int t = 0; t < 3; ++t) {
    const int i0 = mt[t] * 32;
    const int qrow = (i0 + l31) * 40;
    short8 q0 = *(const short8*)&Qb[qrow + half * 8];
    short8 q1 = *(const short8*)&Qb[qrow + 16 + half * 8];

    f32x16 O;
#pragma unroll
    for (int r = 0; r < 16; ++r) O[r] = 0.f;
    float m_run = -3.0e38f, l_run = 0.f;

    for (int j0 = 0; j0 < NP; j0 += 32) {
      // bias loads issued first (independent of mfma)
      float bias[16];
#pragma unroll
      for (int r = 0; r < 16; ++r) {
        int jr = (r & 3) + ((r >> 2) << 3) + (half << 2);
        bias[r] = bh_ptr[(size_t)(j0 + jr) * NP + i0 + l31];
      }
      const int krow = (j0 + l31) * 40;
      short8 ka0 = *(const short8*)&Kb[krow + half * 8];
      short8 ka1 = *(const short8*)&Kb[krow + 16 + half * 8];

      f32x16 T;
#pragma unroll
      for (int r = 0; r < 16; ++r) T[r] = 0.f;
      T = __builtin_amdgcn_mfma_f32_32x32x16_bf16(ka0, q0, T, 0, 0, 0);
      T = __builtin_amdgcn_mfma_f32_32x32x16_bf16(ka1, q1, T, 0, 0, 0);

      float s[16];
      float pm = -3.0e38f;
#pragma unroll
      for (int r = 0; r < 16; ++r) { s[r] = T[r] + bias[r]; pm = fmaxf(pm, s[r]); }
      pm = fmaxf(pm, __shfl_xor(pm, 32, 64));

      if (__any(pm > m_run + 8.0f)) {   // deferred-max rescale (rare)
        float nm = fmaxf(m_run, pm);
        float f = __expf(m_run - nm);
        l_run *= f;
        m_run = nm;
#pragma unroll
        for (int r = 0; r < 16; ++r) {
          int iD = (r & 3) + ((r >> 2) << 3) + (half << 2);
          float fr = __shfl(f, iD, 64);
          O[r] *= fr;
        }
      }

      float psum = 0.f;
      unsigned pk[8];
#pragma unroll
      for (int r = 0; r < 16; r += 2) {
        float p0 = __expf(s[r] - m_run);
        float p1 = __expf(s[r + 1] - m_run);
        psum += p0 + p1;
        pk[r >> 1] = pack2bf(p0, p1);
      }
      l_run += psum + __shfl_xor(psum, 32, 64);

      unsigned sk[8];
#pragma unroll
      for (int u = 0; u < 8; ++u) sk[u] = (unsigned)__shfl_xor((int)pk[u], 32, 64);

      uint4v f1, f2;
      f1[0] = half ? sk[2] : pk[0];  f1[1] = half ? sk[3] : pk[1];
      f1[2] = half ? pk[2] : sk[0];  f1[3] = half ? pk[3] : sk[1];
      f2[0] = half ? sk[6] : pk[4];  f2[1] = half ? sk[7] : pk[5];
      f2[2] = half ? pk[6] : sk[4];  f2[3] = half ? pk[7] : sk[5];
      short8 pa1 = __builtin_bit_cast(short8, f1);
      short8 pa2 = __builtin_bit_cast(short8, f2);

      const int vrow = l31 * 368 + j0;
      short8 vb1 = *(const short8*)&Vt[vrow + half * 8];
      short8 vb2 = *(const short8*)&Vt[vrow + 16 + half * 8];
      O = __builtin_amdgcn_mfma_f32_32x32x16_bf16(pa1, vb1, O, 0, 0, 0);
      O = __builtin_amdgcn_mfma_f32_32x32x16_bf16(pa2, vb2, O, 0, 0, 0);
    }

    float inv = 1.0f / l_run;
#pragma unroll
    for (int r = 0; r < 16; ++r) {
      int iD = (r & 3) + ((r >> 2) << 3) + (half << 2);
      float invr = __shfl(inv, iD, 64);
      int i = i0 + iD;
      if (i < N) outw[(size_t)i * DIM + l31] = O[r] * invr;
    }
  }
}

// ---------------------------------------------------------------------------
// Kernel 3: out-projection, in-place on d_out, hi/lo split MFMA.
// One block per window, 512 threads (8 waves). Tiles: 11(M) x 4(N).
// ---------------------------------------------------------------------------
__global__ __launch_bounds__(512, 2) void proj_kernel(
    const float* __restrict__ wout, float* __restrict__ out) {
  const int w = blockIdx.x;
  const int tid = threadIdx.x;
  const int lane = tid & 63, wv = tid >> 6, l31 = lane & 31, half = lane >> 5;
  __shared__ __align__(16) char smem[76800];
  unsigned short* Oh = (unsigned short*)smem;             // [352][40]
  unsigned short* Ol = (unsigned short*)(smem + 28160);
  unsigned short* W2h = (unsigned short*)(smem + 56320);  // [128][40]
  unsigned short* W2l = (unsigned short*)(smem + 66560);
  float* ow = out + (size_t)w * N * DIM;

  f32x16 acc[6];
#pragma unroll
  for (int s = 0; s < 6; ++s)
#pragma unroll
    for (int r = 0; r < 16; ++r) acc[s][r] = 0.f;

  for (int kc = 0; kc < 4; ++kc) {
    __syncthreads();
#pragma unroll
    for (int p = 0; p < 11; ++p) {
      int idx = tid + p * 512;
      int row = idx >> 4, cp = (idx & 15) << 1;
      float a = 0.f, b = 0.f;
      if (row < N) { const float* g = ow + row * DIM + kc * 32 + cp; a = g[0]; b = g[1]; }
      unsigned hi, lo; split2(a, b, hi, lo);
      *(unsigned*)&Oh[row * 40 + cp] = hi;
      *(unsigned*)&Ol[row * 40 + cp] = lo;
    }
#pragma unroll
    for (int p = 0; p < 8; ++p) {
      int idx = tid + p * 512;
      int k = idx >> 7, n = idx & 127;
      float v = wout[(size_t)(kc * 32 + k) * DIM + n];
      unsigned short hv = bf16u(v);
      W2h[n * 40 + k] = hv;
      W2l[n * 40 + k] = bf16u(v - bf16tof(hv));
    }
    __syncthreads();
#pragma unroll
    for (int s = 0; s < 6; ++s) {
      int id = wv + (s << 3);
      if (id < 44) {
        int mt5 = id >> 2, nt = id & 3;
        int rb = (mt5 * 32 + l31) * 40;
#pragma unroll
        for (int kk = 0; kk < 2; ++kk) {
          short8 ah = *(const short8*)&Oh[rb + kk * 16 + half * 8];
          short8 al = *(const short8*)&Ol[rb + kk * 16 + half * 8];
          int wb = (nt * 32 + l31) * 40 + kk * 16 + half * 8;
          short8 bh = *(const short8*)&W2h[wb];
          short8 bl = *(const short8*)&W2l[wb];
          acc[s] = __builtin_amdgcn_mfma_f32_32x32x16_bf16(ah, bh, acc[s], 0, 0, 0);
          acc[s] = __builtin_amdgcn_mfma_f32_32x32x16_bf16(ah, bl, acc[s], 0, 0, 0);
          acc[s] = __builtin_amdgcn_mfma_f32_32x32x16_bf16(al, bh, acc[s], 0, 0, 0);
        }
      }
    }
  }
#pragma unroll
  for (int s = 0; s < 6; ++s) {
    int id = wv + (s << 3);
    if (id < 44) {
      int mt5 = id >> 2, nt = id & 3;
#pragma unroll
      for (int r = 0; r < 16; ++r) {
        int iD = (r & 3) + ((r >> 2) << 3) + (half << 2);
        int i = mt5 * 32 + iD;
        if (i < N) ow[(size_t)i * DIM + nt * 32 + l31] = acc[s][r];
      }
    }
  }
}

// ---------------------------------------------------------------------------
extern "C" void kernel_launch(void* const* d_in, const int* in_sizes, int n_in,
                              void* d_out, int out_size, void* d_ws, size_t ws_size,
                              hipStream_t stream) {
  const float* x     = (const float*)d_in[0];
  const float* wqkv  = (const float*)d_in[1];
  const float* wout  = (const float*)d_in[2];
  const float* table = (const float*)d_in[3];
  const int*   rel   = (const int*)d_in[4];
  float* out   = (float*)d_out;
  float* biasP = (float*)d_ws;  // 4*352*352*4 B = 1.98 MB

  const int B = in_sizes[0] / (N * DIM);  // 512 windows

  bias_kernel<<<(HEADS * NP * NP + 255) / 256, 256, 0, stream>>>(table, rel, biasP);
  attn_kernel<<<dim3(HEADS, B), 256, 0, stream>>>(x, wqkv, biasP, out);
  proj_kernel<<<B, 512, 0, stream>>>(wout, out);
}

// Round 5
// 304.085 us; speedup vs baseline: 6.4617x; 1.5659x over previous
//
#include <hip/hip_runtime.h>

#define N 343        // 7*7*7 tokens per window
#define NP 352       // padded to 11 tiles of 32
#define DIM 128
#define HEADS 4
#define DH 32

typedef float  f32x16 __attribute__((ext_vector_type(16)));
typedef float  float4v __attribute__((ext_vector_type(4)));
typedef short  short8 __attribute__((ext_vector_type(8)));
typedef unsigned uint4v __attribute__((ext_vector_type(4)));
typedef unsigned uint2v __attribute__((ext_vector_type(2)));

// ---- gfx950 packed bf16 convert (RNE) and cross-half swap -----------------
static __device__ __forceinline__ unsigned cvtpk_bf16(float lo, float hi) {
  unsigned r;
  asm("v_cvt_pk_bf16_f32 %0, %1, %2" : "=v"(r) : "v"(lo), "v"(hi));
  return r;
}
static __device__ __forceinline__ void swap32(unsigned &a, unsigned &b) {
  // a.hi32lanes <-> b.lo32lanes
  asm("v_permlane32_swap_b32 %0, %1" : "+v"(a), "+v"(b));
}
// native base-2 exponential (v_exp_f32 IS exp2 on gfx9/CDNA)
static __device__ __forceinline__ float exp2v(float x) {
  float r;
  asm("v_exp_f32 %0, %1" : "=v"(r) : "v"(x));
  return r;
}
static __device__ __forceinline__ unsigned short bf16u(float a) {
  unsigned u = __builtin_bit_cast(unsigned, a);
  unsigned r = u + 0x7fffu + ((u >> 16) & 1u);
  return (unsigned short)(r >> 16);
}
// split (a,b) into packed bf16 hi + lo parts (hi: a->low16, b->high16)
static __device__ __forceinline__ void split2pk(float a, float b,
                                                unsigned &hi, unsigned &lo) {
  hi = cvtpk_bf16(a, b);
  float ra = a - __builtin_bit_cast(float, hi << 16);
  float rb = b - __builtin_bit_cast(float, hi & 0xffff0000u);
  lo = cvtpk_bf16(ra, rb);
}

// ---------------------------------------------------------------------------
// Kernel 1: bias gather pre-permuted into the 32x32 MFMA C-fragment order so
// phase 2 loads it as one f32x16 straight into the MFMA C operand.
// Row = (h, jt, half, i); 16 floats = r-ordered bias(j(r,half), i) * log2(e).
// j >= 343 -> -1.44e30 (masks pad keys).
// ---------------------------------------------------------------------------
__global__ __launch_bounds__(256) void bias_kernel(
    const float* __restrict__ table, const int* __restrict__ rel,
    float* __restrict__ prep) {
  int row = blockIdx.x * 256 + threadIdx.x;
  if (row >= HEADS * 11 * 2 * NP) return;
  int i = row % NP;
  int t = row / NP;
  int half = t & 1;
  int tj = t >> 1;
  int jt = tj % 11;
  int h = tj / 11;
  float* dst = prep + (size_t)row * 16;
#pragma unroll
  for (int r = 0; r < 16; ++r) {
    int j = jt * 32 + (r & 3) + ((r >> 2) << 3) + (half << 2);
    float v;
    if (j >= N) v = -1.44e30f;
    else if (i >= N) v = 0.f;
    else v = table[rel[i * N + j] * HEADS + h] * 1.4426950408889634f;
    dst[r] = v;
  }
}

// ---------------------------------------------------------------------------
// Kernel 2: fused QKV projection + attention. One block per (window, head),
// 384 threads = 6 waves, launch_bounds(384,3) -> 12 waves/CU.
// XCD-swizzled blockIdx so a window's 4 heads share one XCD's L2 (x reuse).
// Phase 1: hi/lo-split bf16 MFMA QKV; phase 2: swapped QK^T + in-register
// exp2-domain online softmax; bias tile IS the MFMA C-input (prefetched).
// ---------------------------------------------------------------------------
__global__ __launch_bounds__(384, 3) void attn_kernel(
    const float* __restrict__ x, const float* __restrict__ wqkv,
    const float* __restrict__ prep, float* __restrict__ out) {
  const int b = blockIdx.x;
  const int sw = (b & 7) * ((int)gridDim.x >> 3) + (b >> 3);  // XCD swizzle
  const int h = sw & 3;
  const int w = sw >> 2;
  const int tid = threadIdx.x;
  const int lane = tid & 63;
  const int wv = tid >> 6;        // 0..5
  const int l31 = lane & 31;
  const int half = lane >> 5;

  __shared__ __align__(16) char smem[80384];
  unsigned short* Xh = (unsigned short*)smem;            // [352][40]
  unsigned short* Xl = (unsigned short*)(smem + 28160);  // [352][40]
  unsigned short* Wh = (unsigned short*)(smem + 56320);  // [96][40]
  unsigned short* Wl = (unsigned short*)(smem + 64000);  // [96][40]
  unsigned short* Qb = (unsigned short*)smem;            // [352][40] (reuse)
  unsigned short* Kb = (unsigned short*)(smem + 28160);  // [352][40] (reuse)
  unsigned short* Vt = (unsigned short*)(smem + 56320);  // [32][376]  (reuse)

  const float* xw = x + (size_t)w * (N * DIM);

  // ---------------- Phase 1: QKV projection ----------------
  f32x16 acc[6];
#pragma unroll
  for (int s = 0; s < 6; ++s)
#pragma unroll
    for (int r = 0; r < 16; ++r) acc[s][r] = 0.f;

  for (int kc = 0; kc < 4; ++kc) {
    __syncthreads();
    // stage X[:, kc*32..+32) as hi/lo bf16 (352 rows x 8 float4-groups)
#pragma unroll
    for (int p = 0; p < 8; ++p) {
      int idx = tid + p * 384;
      if (idx < 2816) {
        int row = idx >> 3, cp = (idx & 7) << 2;
        float4v g = {0.f, 0.f, 0.f, 0.f};
        if (row < N) g = *(const float4v*)(xw + row * DIM + kc * 32 + cp);
        unsigned h0, l0, h1, l1;
        split2pk(g[0], g[1], h0, l0);
        split2pk(g[2], g[3], h1, l1);
        uint2v hv = {h0, h1}, lv = {l0, l1};
        *(uint2v*)&Xh[row * 40 + cp] = hv;
        *(uint2v*)&Xl[row * 40 + cp] = lv;
      }
    }
    // stage W slice transposed: [c 0..95][k 0..31], 768 float4-groups
#pragma unroll
    for (int p = 0; p < 2; ++p) {
      int idx = tid + p * 384;
      int k = idx / 24, cg = idx - k * 24;
      int c0 = cg << 2;
      int col = ((c0 >> 5) << 7) + h * DH + (c0 & 31);
      float4v g = *(const float4v*)(wqkv + (size_t)(kc * 32 + k) * (3 * DIM) + col);
#pragma unroll
      for (int u = 0; u < 4; ++u) {
        unsigned short hv = bf16u(g[u]);
        Wh[(c0 + u) * 40 + k] = hv;
        Wl[(c0 + u) * 40 + k] =
            bf16u(g[u] - __builtin_bit_cast(float, (unsigned)hv << 16));
      }
    }
    __syncthreads();
#pragma unroll
    for (int s = 0; s < 6; ++s) {
      int id = wv + s * 6;
      if (id < 33) {
        int mt = id % 11, nt = id / 11;
        int rb = (mt * 32 + l31) * 40 + half * 8;
        int wb = (nt * 32 + l31) * 40 + half * 8;
#pragma unroll
        for (int kk = 0; kk < 2; ++kk) {
          short8 ah = *(const short8*)&Xh[rb + kk * 16];
          short8 al = *(const short8*)&Xl[rb + kk * 16];
          short8 bh = *(const short8*)&Wh[wb + kk * 16];
          short8 bl = *(const short8*)&Wl[wb + kk * 16];
          acc[s] = __builtin_amdgcn_mfma_f32_32x32x16_bf16(ah, bh, acc[s], 0, 0, 0);
          acc[s] = __builtin_amdgcn_mfma_f32_32x32x16_bf16(ah, bl, acc[s], 0, 0, 0);
          acc[s] = __builtin_amdgcn_mfma_f32_32x32x16_bf16(al, bh, acc[s], 0, 0, 0);
        }
      }
    }
  }

  // ---------------- phase boundary: regs -> Q/K/Vt LDS ----------------
  __syncthreads();
  const float QSCALE = 0.17677669529663687f * 1.4426950408889634f; // /sqrt(32)*log2e
#pragma unroll
  for (int s = 0; s < 6; ++s) {
    int id = wv + s * 6;
    if (id < 33) {
      int mt = id % 11, nt = id / 11;
      if (nt == 2) {
        int vb = l31 * 376 + mt * 32;
#pragma unroll
        for (int r = 0; r < 16; r += 2) {
          int iD = (r & 3) + ((r >> 2) << 3) + (half << 2);
          *(unsigned*)&Vt[vb + iD] = cvtpk_bf16(acc[s][r], acc[s][r + 1]);
        }
      } else {
        unsigned short* dst = (nt == 0) ? Qb : Kb;
        float sc = (nt == 0) ? QSCALE : 1.f;
#pragma unroll
        for (int r = 0; r < 16; ++r) {
          int iD = (r & 3) + ((r >> 2) << 3) + (half << 2);
          dst[(mt * 32 + iD) * 40 + l31] = bf16u(acc[s][r] * sc);
        }
      }
    }
  }
  __syncthreads();

  // ---------------- Phase 2: attention ----------------
  const float* bp = prep + ((size_t)(h * 22 + half) * NP) * 16;
  float* outw = out + (size_t)w * N * DIM + h * DH;

#pragma unroll
  for (int t = 0; t < 2; ++t) {
    const int mt = wv + t * 6;
    if (mt < 11) {
      const int i0 = mt * 32;
      const int qrow = (i0 + l31) * 40 + half * 8;
      short8 q0 = *(const short8*)&Qb[qrow];
      short8 q1 = *(const short8*)&Qb[qrow + 16];
      const float* bpi = bp + (size_t)(i0 + l31) * 16;

      f32x16 O;
#pragma unroll
      for (int r = 0; r < 16; ++r) O[r] = 0.f;
      float m_run = -3.0e38f, l_run = 0.f;

      f32x16 Tn = *(const f32x16*)(bpi);    // prefetch bias tile 0
      for (int jt = 0; jt < 11; ++jt) {
        f32x16 T = Tn;                       // bias IS the MFMA C-input
        if (jt < 10) Tn = *(const f32x16*)(bpi + (size_t)(jt + 1) * 11264);

        const int krow = (jt * 32 + l31) * 40 + half * 8;
        short8 ka0 = *(const short8*)&Kb[krow];
        short8 ka1 = *(const short8*)&Kb[krow + 16];
        T = __builtin_amdgcn_mfma_f32_32x32x16_bf16(ka0, q0, T, 0, 0, 0);
        T = __builtin_amdgcn_mfma_f32_32x32x16_bf16(ka1, q1, T, 0, 0, 0);

        // per-lane max, tree depth 4 + cross-half
        float m0 = fmaxf(T[0], T[1]),   m1 = fmaxf(T[2], T[3]);
        float m2 = fmaxf(T[4], T[5]),   m3 = fmaxf(T[6], T[7]);
        float m4 = fmaxf(T[8], T[9]),   m5 = fmaxf(T[10], T[11]);
        float m6 = fmaxf(T[12], T[13]), m7 = fmaxf(T[14], T[15]);
        m0 = fmaxf(m0, m1); m2 = fmaxf(m2, m3);
        m4 = fmaxf(m4, m5); m6 = fmaxf(m6, m7);
        m0 = fmaxf(m0, m2); m4 = fmaxf(m4, m6);
        float pm = fmaxf(m0, m4);
        pm = fmaxf(pm, __shfl_xor(pm, 32, 64));

        if (__any(pm > m_run + 11.5f)) {   // deferred-max rescale (rare)
          float nm = fmaxf(m_run, pm);
          float f = exp2v(m_run - nm);
          l_run *= f;
          m_run = nm;
#pragma unroll
          for (int r = 0; r < 16; ++r) {
            int iD = (r & 3) + ((r >> 2) << 3) + (half << 2);
            O[r] *= __shfl(f, iD, 64);
          }
        }

        float p[16];
#pragma unroll
        for (int r = 0; r < 16; ++r) p[r] = exp2v(T[r] - m_run);
        float s0 = (p[0] + p[1]) + (p[2] + p[3]);
        float s1 = (p[4] + p[5]) + (p[6] + p[7]);
        float s2 = (p[8] + p[9]) + (p[10] + p[11]);
        float s3 = (p[12] + p[13]) + (p[14] + p[15]);
        float ps = (s0 + s1) + (s2 + s3);
        l_run += ps + __shfl_xor(ps, 32, 64);

        // P -> PV A-fragment: 8 cvt_pk + 4 permlane32_swap
        unsigned k0 = cvtpk_bf16(p[0], p[1]),   k1 = cvtpk_bf16(p[2], p[3]);
        unsigned k2 = cvtpk_bf16(p[4], p[5]),   k3 = cvtpk_bf16(p[6], p[7]);
        unsigned k4 = cvtpk_bf16(p[8], p[9]),   k5 = cvtpk_bf16(p[10], p[11]);
        unsigned k6 = cvtpk_bf16(p[12], p[13]), k7 = cvtpk_bf16(p[14], p[15]);
        swap32(k0, k2); swap32(k1, k3); swap32(k4, k6); swap32(k5, k7);
        uint4v u1 = {k0, k1, k2, k3};
        uint4v u2 = {k4, k5, k6, k7};
        short8 pa1 = __builtin_bit_cast(short8, u1);
        short8 pa2 = __builtin_bit_cast(short8, u2);

        const int vrow = l31 * 376 + jt * 32 + half * 8;
        short8 vb1 = *(const short8*)&Vt[vrow];
        short8 vb2 = *(const short8*)&Vt[vrow + 16];
        O = __builtin_amdgcn_mfma_f32_32x32x16_bf16(pa1, vb1, O, 0, 0, 0);
        O = __builtin_amdgcn_mfma_f32_32x32x16_bf16(pa2, vb2, O, 0, 0, 0);
      }

      float inv = 1.0f / l_run;
#pragma unroll
      for (int r = 0; r < 16; ++r) {
        int iD = (r & 3) + ((r >> 2) << 3) + (half << 2);
        float invr = __shfl(inv, iD, 64);
        int i = i0 + iD;
        if (i < N) outw[(size_t)i * DIM + l31] = O[r] * invr;
      }
    }
  }
}

// ---------------------------------------------------------------------------
// Kernel 3: out-projection, in-place on d_out, hi/lo split MFMA.
// One block per window, 512 threads (8 waves). Tiles: 11(M) x 4(N).
// ---------------------------------------------------------------------------
__global__ __launch_bounds__(512, 2) void proj_kernel(
    const float* __restrict__ wout, float* __restrict__ out) {
  const int w = blockIdx.x;
  const int tid = threadIdx.x;
  const int lane = tid & 63, wv = tid >> 6, l31 = lane & 31, half = lane >> 5;
  __shared__ __align__(16) char smem[76800];
  unsigned short* Oh = (unsigned short*)smem;             // [352][40]
  unsigned short* Ol = (unsigned short*)(smem + 28160);
  unsigned short* W2h = (unsigned short*)(smem + 56320);  // [128][40]
  unsigned short* W2l = (unsigned short*)(smem + 66560);
  float* ow = out + (size_t)w * N * DIM;

  f32x16 acc[6];
#pragma unroll
  for (int s = 0; s < 6; ++s)
#pragma unroll
    for (int r = 0; r < 16; ++r) acc[s][r] = 0.f;

  for (int kc = 0; kc < 4; ++kc) {
    __syncthreads();
#pragma unroll
    for (int p = 0; p < 11; ++p) {
      int idx = tid + p * 512;
      int row = idx >> 4, cp = (idx & 15) << 1;
      float a = 0.f, bb = 0.f;
      if (row < N) { const float* g = ow + row * DIM + kc * 32 + cp; a = g[0]; bb = g[1]; }
      unsigned hi, lo; split2pk(a, bb, hi, lo);
      *(unsigned*)&Oh[row * 40 + cp] = hi;
      *(unsigned*)&Ol[row * 40 + cp] = lo;
    }
#pragma unroll
    for (int p = 0; p < 8; ++p) {
      int idx = tid + p * 512;
      int k = idx >> 7, n = idx & 127;
      float v = wout[(size_t)(kc * 32 + k) * DIM + n];
      unsigned short hv = bf16u(v);
      W2h[n * 40 + k] = hv;
      W2l[n * 40 + k] = bf16u(v - __builtin_bit_cast(float, (unsigned)hv << 16));
    }
    __syncthreads();
#pragma unroll
    for (int s = 0; s < 6; ++s) {
      int id = wv + (s << 3);
      if (id < 44) {
        int mt5 = id >> 2, nt = id & 3;
        int rb = (mt5 * 32 + l31) * 40;
#pragma unroll
        for (int kk = 0; kk < 2; ++kk) {
          short8 ah = *(const short8*)&Oh[rb + kk * 16 + half * 8];
          short8 al = *(const short8*)&Ol[rb + kk * 16 + half * 8];
          int wb = (nt * 32 + l31) * 40 + kk * 16 + half * 8;
          short8 bh = *(const short8*)&W2h[wb];
          short8 bl = *(const short8*)&W2l[wb];
          acc[s] = __builtin_amdgcn_mfma_f32_32x32x16_bf16(ah, bh, acc[s], 0, 0, 0);
          acc[s] = __builtin_amdgcn_mfma_f32_32x32x16_bf16(ah, bl, acc[s], 0, 0, 0);
          acc[s] = __builtin_amdgcn_mfma_f32_32x32x16_bf16(al, bh, acc[s], 0, 0, 0);
        }
      }
    }
  }
#pragma unroll
  for (int s = 0; s < 6; ++s) {
    int id = wv + (s << 3);
    if (id < 44) {
      int mt5 = id >> 2, nt = id & 3;
#pragma unroll
      for (int r = 0; r < 16; ++r) {
        int iD = (r & 3) + ((r >> 2) << 3) + (half << 2);
        int i = mt5 * 32 + iD;
        if (i < N) ow[(size_t)i * DIM + nt * 32 + l31] = acc[s][r];
      }
    }
  }
}

// ---------------------------------------------------------------------------
extern "C" void kernel_launch(void* const* d_in, const int* in_sizes, int n_in,
                              void* d_out, int out_size, void* d_ws, size_t ws_size,
                              hipStream_t stream) {
  const float* x     = (const float*)d_in[0];
  const float* wqkv  = (const float*)d_in[1];
  const float* wout  = (const float*)d_in[2];
  const float* table = (const float*)d_in[3];
  const int*   rel   = (const int*)d_in[4];
  float* out  = (float*)d_out;
  float* prep = (float*)d_ws;  // 4*11*2*352*16*4 B = 1.98 MB

  const int B = in_sizes[0] / (N * DIM);  // 512 windows
  const int rows = HEADS * 11 * 2 * NP;   // 30976

  bias_kernel<<<(rows + 255) / 256, 256, 0, stream>>>(table, rel, prep);
  attn_kernel<<<HEADS * B, 384, 0, stream>>>(x, wqkv, prep, out);
  proj_kernel<<<B, 512, 0, stream>>>(wout, out);
}